// Round 1
// baseline (144.674 us; speedup 1.0000x reference)
//
#include <hip/hip_runtime.h>
#include <math.h>

#define NUM_E   100000
#define GAMMA_F 12.0f
#define EMB_RANGE_F 0.21875f                       // (12+2)/64
#define INV_TWO_EMB (1.0f / (2.0f * EMB_RANGE_F))  // rev = r * this = phase/(2pi)

#define NBLK  1024                                 // 4 blocks/CU exactly
#define NWAVE (NBLK * 4)                           // 4096 waves, stride

typedef float v4f __attribute__((ext_vector_type(4)));
typedef float v2f __attribute__((ext_vector_type(2)));

// ---- packed-f32 VALU (VOP3P): 2 dims per instruction ----
static __device__ __forceinline__ v2f pk_sub(v2f a, v2f b) {
    v2f d;
    asm("v_pk_add_f32 %0, %1, %2 neg_lo:[0,1] neg_hi:[0,1]"
        : "=v"(d) : "v"(a), "v"(b));
    return d;
}
static __device__ __forceinline__ v2f pk_mul(v2f a, v2f b) {
    v2f d;
    asm("v_pk_mul_f32 %0, %1, %2" : "=v"(d) : "v"(a), "v"(b));
    return d;
}
static __device__ __forceinline__ v2f pk_fma(v2f a, v2f b, v2f c) {
    v2f d;
    asm("v_pk_fma_f32 %0, %1, %2, %3" : "=v"(d) : "v"(a), "v"(b), "v"(c));
    return d;
}
static __device__ __forceinline__ float sq2(v2f dx, v2f dy) {
    v2f sq = pk_fma(dy, dy, pk_mul(dx, dx));
    return __builtin_amdgcn_sqrtf(sq.x) + __builtin_amdgcn_sqrtf(sq.y);
}
static __device__ __forceinline__ v2f lo2(v4f v) { return __builtin_shufflevector(v, v, 0, 1); }
static __device__ __forceinline__ v2f hi2(v4f v) { return __builtin_shufflevector(v, v, 2, 3); }

// cross-lane add via DPP quad_perm (VALU pipe, not DS)
template <int CTRL>
static __device__ __forceinline__ float dpp_xor_add(float x) {
    int y = __builtin_amdgcn_update_dpp(0, __float_as_int(x), CTRL, 0xF, 0xF, true);
    return x + __int_as_float(y);
}

// R7: single fused persistent kernel.
//  - Each wave computes its own rot slice (4 batches x 8 dims x {re,im} = 64 f32)
//    ONCE with v_sin/v_cos, and holds it in 64 VGPRs for the whole kernel
//    (launch_bounds(256,4) -> 128-VGPR budget; the old kernel's VGPR=56 proved
//    the compiler was rematerializing rot via 16 dwordx4 L1 loads per 4 entities).
//  - No LDS. Entity rows read straight from global; the 8 bg-lanes sharing a dg
//    read identical 16B chunks -> coalescer dedups 8x (512B/entity/wave).
//  - Grid-stride at 1 entity/wave/iter with 1-deep register prefetch of the
//    next entity (covers L2/L3 latency under ~520cy of compute).
//  - Tail: 100000 entities / 4096 waves = 24..25 iters/wave (~4% imbalance)
//    vs the old 8-entity-task ceil(1.53)=2 rounds (~30% tail).
__global__ __launch_bounds__(256, 4) void rotate_dist_fused(
        const int*   __restrict__ facts,
        const float* __restrict__ ent,
        const float* __restrict__ rel,
        float*       __restrict__ out) {
    const int t    = threadIdx.x;
    const int lane = t & 63;
    const int wv   = t >> 6;
    const int bg   = lane >> 3;         // batches 4bg..4bg+3
    const int dg   = lane & 7;          // dims 8dg..8dg+7
    const int wid  = blockIdx.x * 4 + wv;   // 0..4095

    // ---- build rot slice in registers (once per wave) ----
    v2f RR[4][4], RI[4][4];
#pragma unroll
    for (int kb = 0; kb < 4; ++kb) {
        const int b  = bg * 4 + kb;
        const int f0 = facts[b * 3 + 0];
        const int f1 = facts[b * 3 + 1];
        const float* hp = ent + (size_t)f0 * 128 + dg * 8;
        const float* rp = rel + (size_t)f1 * 64  + dg * 8;
        float hre[8], him[8], ph[8];
        *(v4f*)&hre[0] = *(const v4f*)(hp);
        *(v4f*)&hre[4] = *(const v4f*)(hp + 4);
        *(v4f*)&him[0] = *(const v4f*)(hp + 64);
        *(v4f*)&him[4] = *(const v4f*)(hp + 68);
        *(v4f*)&ph[0]  = *(const v4f*)(rp);
        *(v4f*)&ph[4]  = *(const v4f*)(rp + 4);
        float rer[8], imr[8];
#pragma unroll
        for (int j = 0; j < 8; ++j) {
            float rev = ph[j] * INV_TWO_EMB;         // phase/(2pi), in [-0.5,0.5]
            float s = __builtin_amdgcn_sinf(rev);    // v_sin_f32: revolutions
            float c = __builtin_amdgcn_cosf(rev);
            rer[j] = hre[j] * c - him[j] * s;
            imr[j] = hre[j] * s + him[j] * c;
        }
#pragma unroll
        for (int j = 0; j < 4; ++j) {
            RR[kb][j] = (v2f){rer[2 * j], rer[2 * j + 1]};
            RI[kb][j] = (v2f){imr[2 * j], imr[2 * j + 1]};
        }
    }

    // lanes with dg<4 store batch bg*4+dg
    float* obase = out + (size_t)(bg * 4 + (dg & 3)) * NUM_E;

    // ---- main loop: 1 entity/iter, 1-deep prefetch ----
    int e = wid;
    {
        const float* ep = ent + (size_t)e * 128 + dg * 8;
        v4f er0 = *(const v4f*)(ep);
        v4f er1 = *(const v4f*)(ep + 4);
        v4f ei0 = *(const v4f*)(ep + 64);
        v4f ei1 = *(const v4f*)(ep + 68);

        while (e < NUM_E) {
            const int en = e + NWAVE;
            const int ec = (en < NUM_E) ? en : e;    // wave-uniform clamp, no branch
            const float* np = ent + (size_t)ec * 128 + dg * 8;
            v4f nr0 = *(const v4f*)(np);
            v4f nr1 = *(const v4f*)(np + 4);
            v4f ni0 = *(const v4f*)(np + 64);
            v4f ni1 = *(const v4f*)(np + 68);

            v2f e2[4] = { lo2(er0), hi2(er0), lo2(er1), hi2(er1) };
            v2f i2[4] = { lo2(ei0), hi2(ei0), lo2(ei1), hi2(ei1) };
            float r[4];
#pragma unroll
            for (int kb = 0; kb < 4; ++kb) {
                float s0 = sq2(pk_sub(RR[kb][0], e2[0]), pk_sub(RI[kb][0], i2[0]));
                float s1 = sq2(pk_sub(RR[kb][1], e2[1]), pk_sub(RI[kb][1], i2[1]));
                float s2 = sq2(pk_sub(RR[kb][2], e2[2]), pk_sub(RI[kb][2], i2[2]));
                float s3 = sq2(pk_sub(RR[kb][3], e2[3]), pk_sub(RI[kb][3], i2[3]));
                float v = (s0 + s1) + (s2 + s3);
                v = dpp_xor_add<0xB1>(v);            // quad_perm [1,0,3,2] : xor1
                v = dpp_xor_add<0x4E>(v);            // quad_perm [2,3,0,1] : xor2
                v += __shfl_xor(v, 4, 64);           // xor4 across dg
                r[kb] = GAMMA_F - v;
            }
            if (dg < 4) {
                float val = (dg == 0) ? r[0] : (dg == 1) ? r[1]
                          : (dg == 2) ? r[2] : r[3];
                obase[e] = val;
            }
            er0 = nr0; er1 = nr1; ei0 = ni0; ei1 = ni1;
            e = en;
        }
    }
}

extern "C" void kernel_launch(void* const* d_in, const int* in_sizes, int n_in,
                              void* d_out, int out_size, void* d_ws, size_t ws_size,
                              hipStream_t stream) {
    const int*   facts = (const int*)d_in[0];
    const float* ent   = (const float*)d_in[1];
    const float* rel   = (const float*)d_in[2];
    float*       out   = (float*)d_out;
    (void)d_ws; (void)ws_size;

    rotate_dist_fused<<<dim3(NBLK), dim3(256), 0, stream>>>(facts, ent, rel, out);
}